// Round 2
// baseline (85.696 us; speedup 1.0000x reference)
//
#include <hip/hip_runtime.h>
#include <hip/hip_bf16.h>
#include <hip/hip_cooperative_groups.h>

namespace cg = cooperative_groups;

#define N_DIMS 128
#define GRID_BLOCKS 512
#define BLOCK 256

// Fused single-launch kernel (cooperative):
//  Phase 0 (block 0): detect index width. Reference src/dst are int64; the
//    harness may deliver int32. Values < 10^4, so for int64 layout every odd
//    32-bit word is 0. For int32, 2048 random odd-position values being all
//    zero has probability ~1e-? (each is 0 w.p. 1e-4) -> negligible.
//  Phase 1: per-node projection tables (the einsum distributed over the
//    gather): tsrc[n][c] = h[n].Wsrc[c], tdst[n][c] = h[n].Wdst[c] + b[c].
//    8 lanes per node, float4 loads, 3-stage shfl_xor reduce.
//  grid.sync()
//  Phase 2: out[e][c] = tsrc[src[e]][c] + tdst[dst[e]][c]; 4 edges/thread,
//    uint4 index loads, 3x float4 output stores. Tables (2x160 KB) are
//    L2-resident; only indices + output touch HBM.
__global__ __launch_bounds__(BLOCK) void hetero_fused(
    const float* __restrict__ h, const float* __restrict__ W,
    const float* __restrict__ b, const unsigned int* __restrict__ src32,
    const unsigned int* __restrict__ dst32,
    float4* __restrict__ tsrc, float4* __restrict__ tdst,
    int* __restrict__ flag, float* __restrict__ out,
    int n_nodes, int n_edges) {
  // ---- Phase 0: index-width detection (block 0 only) ----
  if (blockIdx.x == 0) {
    __shared__ int nz;
    if (threadIdx.x == 0) nz = 0;
    __syncthreads();
    int samples = n_edges < 2048 ? n_edges : 2048;
    int local = 0;
    for (int i = threadIdx.x; i < samples; i += BLOCK)
      local |= (src32[2 * i + 1] != 0u) ? 1 : 0;
    if (local) nz = 1;  // benign race: all writers store 1
    __syncthreads();
    if (threadIdx.x == 0) flag[0] = nz ? 0 : 1;  // 1 => int64 layout
  }

  // ---- Phase 1: projection, 8 lanes per node ----
  {
    const float4* h4 = (const float4*)h;
    const float4* W4 = (const float4*)W;  // W row = 256 floats = 64 float4
    int wave = (blockIdx.x * BLOCK + threadIdx.x) >> 6;
    int lane = threadIdx.x & 63;
    int g    = lane >> 3;    // 8 nodes per wave
    int sub  = lane & 7;     // 8 lanes per node, 16 dims each
    int node = wave * 8 + g; // 2048 waves * 8 = 16384 >= n_nodes, single pass
    if (node < n_nodes) {
      float acc[6] = {0.f, 0.f, 0.f, 0.f, 0.f, 0.f};
#pragma unroll
      for (int k = 0; k < 4; ++k) {
        float4 hv = h4[(size_t)node * 32 + sub * 4 + k];
#pragma unroll
        for (int c = 0; c < 3; ++c) {
          float4 ws = W4[c * 64 + sub * 4 + k];
          float4 wd = W4[c * 64 + 32 + sub * 4 + k];
          acc[c]     += hv.x * ws.x + hv.y * ws.y + hv.z * ws.z + hv.w * ws.w;
          acc[3 + c] += hv.x * wd.x + hv.y * wd.y + hv.z * wd.z + hv.w * wd.w;
        }
      }
#pragma unroll
      for (int off = 1; off <= 4; off <<= 1) {
#pragma unroll
        for (int k = 0; k < 6; ++k) acc[k] += __shfl_xor(acc[k], off, 64);
      }
      if (sub == 0) {
        tsrc[node] = make_float4(acc[0], acc[1], acc[2], 0.f);
        tdst[node] = make_float4(acc[3] + b[0], acc[4] + b[1], acc[5] + b[2], 0.f);
      }
    }
  }

  cg::this_grid().sync();

  // ---- Phase 2: gather-add, 4 edges per thread ----
  int shift = flag[0];
  int gtid  = blockIdx.x * BLOCK + threadIdx.x;
  int e0    = gtid * 4;  // 512*256*4 = 524288 >= n_edges, single pass
  if (e0 + 3 < n_edges) {
    unsigned s[4], d[4];
    const uint4* sp = (const uint4*)(src32 + ((size_t)e0 << shift));
    const uint4* dp = (const uint4*)(dst32 + ((size_t)e0 << shift));
    if (shift) {  // int64: 8 dwords, take even words
      uint4 a = sp[0], bb = sp[1];
      s[0] = a.x; s[1] = a.z; s[2] = bb.x; s[3] = bb.z;
      uint4 c = dp[0], dd = dp[1];
      d[0] = c.x; d[1] = c.z; d[2] = dd.x; d[3] = dd.z;
    } else {      // int32: 4 dwords
      uint4 a = sp[0]; s[0] = a.x; s[1] = a.y; s[2] = a.z; s[3] = a.w;
      uint4 c = dp[0]; d[0] = c.x; d[1] = c.y; d[2] = c.z; d[3] = c.w;
    }
    float r[12];
#pragma unroll
    for (int k = 0; k < 4; ++k) {
      float4 a = tsrc[s[k]];
      float4 c = tdst[d[k]];
      r[k * 3 + 0] = a.x + c.x;
      r[k * 3 + 1] = a.y + c.y;
      r[k * 3 + 2] = a.z + c.z;
    }
    float4* o4 = (float4*)(out + (size_t)e0 * 3);  // e0*12 bytes, 16B aligned
    o4[0] = make_float4(r[0], r[1], r[2],  r[3]);
    o4[1] = make_float4(r[4], r[5], r[6],  r[7]);
    o4[2] = make_float4(r[8], r[9], r[10], r[11]);
  } else if (e0 < n_edges) {
    for (int e = e0; e < n_edges; ++e) {
      unsigned s = src32[(size_t)e << shift];
      unsigned d = dst32[(size_t)e << shift];
      float4 a = tsrc[s];
      float4 c = tdst[d];
      out[(size_t)e * 3 + 0] = a.x + c.x;
      out[(size_t)e * 3 + 1] = a.y + c.y;
      out[(size_t)e * 3 + 2] = a.z + c.z;
    }
  }
}

extern "C" void kernel_launch(void* const* d_in, const int* in_sizes, int n_in,
                              void* d_out, int out_size, void* d_ws, size_t ws_size,
                              hipStream_t stream) {
  const float*        h     = (const float*)d_in[0];
  const unsigned int* src32 = (const unsigned int*)d_in[1];
  const unsigned int* dst32 = (const unsigned int*)d_in[2];
  const float*        W     = (const float*)d_in[3];
  const float*        b     = (const float*)d_in[4];
  float*              out   = (float*)d_out;

  int n_nodes = in_sizes[0] / N_DIMS;  // 10000
  int n_edges = in_sizes[1];           // 500000

  char*   ws   = (char*)d_ws;
  float4* tsrc = (float4*)(ws);
  float4* tdst = (float4*)(ws + (size_t)n_nodes * sizeof(float4));
  int*    flag = (int*)(ws + 2 * (size_t)n_nodes * sizeof(float4));

  void* args[] = {&h, &W, &b, &src32, &dst32, &tsrc, &tdst, &flag, &out,
                  &n_nodes, &n_edges};
  hipLaunchCooperativeKernel(reinterpret_cast<void*>(hetero_fused),
                             dim3(GRID_BLOCKS), dim3(BLOCK), args, 0, stream);
}

// Round 3
// 17.790 us; speedup vs baseline: 4.8171x; 4.8171x over previous
//
#include <hip/hip_runtime.h>
#include <hip/hip_bf16.h>

#define N_DIMS 128
#define BLOCK 256

// ---------------------------------------------------------------------------
// Kernel 1: per-node projection tables + index-width detection.
//   tsrc[n][c] = h[n] . Wsrc[c]
//   tdst[n][c] = h[n] . Wdst[c] + b[c]        (c = 0..2)
// The einsum distributed over the gather: tables are 10000 x float4 each
// (~320 KB total), L2-resident for kernel 2.
// 8 lanes per node (16 dims / lane via 4x float4), 3-stage shfl_xor reduce.
// Block 0 probes src's odd 32-bit words: reference dtype is int64 but the
// harness may deliver int32. Values < 10^4 => int64 high words are all 0;
// for int32 random values, 2048 odd-position words all-zero is ~impossible.
// ---------------------------------------------------------------------------
__global__ __launch_bounds__(BLOCK) void hetero_proj_detect(
    const float* __restrict__ h, const float* __restrict__ W,
    const float* __restrict__ b, const unsigned int* __restrict__ src32,
    float4* __restrict__ tsrc, float4* __restrict__ tdst,
    int* __restrict__ flag, int n_nodes, int n_edges) {
  if (blockIdx.x == 0) {
    __shared__ int nz;
    if (threadIdx.x == 0) nz = 0;
    __syncthreads();
    int samples = n_edges < 2048 ? n_edges : 2048;
    int local = 0;
    for (int i = threadIdx.x; i < samples; i += BLOCK)
      local |= (src32[2 * i + 1] != 0u) ? 1 : 0;
    if (local) nz = 1;  // benign race: all writers store 1
    __syncthreads();
    if (threadIdx.x == 0) flag[0] = nz ? 0 : 1;  // 1 => int64 layout
  }

  const float4* h4 = (const float4*)h;
  const float4* W4 = (const float4*)W;  // W row = 256 floats = 64 float4
  int wave = (blockIdx.x * BLOCK + threadIdx.x) >> 6;
  int lane = threadIdx.x & 63;
  int g    = lane >> 3;     // 8 nodes per wave
  int sub  = lane & 7;      // 8 lanes per node, 16 dims each
  int node = wave * 8 + g;
  if (node >= n_nodes) return;

  float acc[6] = {0.f, 0.f, 0.f, 0.f, 0.f, 0.f};
#pragma unroll
  for (int k = 0; k < 4; ++k) {
    float4 hv = h4[(size_t)node * 32 + sub * 4 + k];
#pragma unroll
    for (int c = 0; c < 3; ++c) {
      float4 ws = W4[c * 64 + sub * 4 + k];
      float4 wd = W4[c * 64 + 32 + sub * 4 + k];
      acc[c]     += hv.x * ws.x + hv.y * ws.y + hv.z * ws.z + hv.w * ws.w;
      acc[3 + c] += hv.x * wd.x + hv.y * wd.y + hv.z * wd.z + hv.w * wd.w;
    }
  }
#pragma unroll
  for (int off = 1; off <= 4; off <<= 1) {
#pragma unroll
    for (int k = 0; k < 6; ++k) acc[k] += __shfl_xor(acc[k], off, 64);
  }
  if (sub == 0) {
    tsrc[node] = make_float4(acc[0], acc[1], acc[2], 0.f);
    tdst[node] = make_float4(acc[3] + b[0], acc[4] + b[1], acc[5] + b[2], 0.f);
  }
}

// ---------------------------------------------------------------------------
// Kernel 2: per-edge gather-add, 4 edges/thread.
//   out[e][c] = tsrc[src[e]][c] + tdst[dst[e]][c]
// uint4 index loads (branch-free for int32/int64 via word stride), three
// aligned float4 stores per thread (12 floats = 4 edges x 3 classes).
// Tables hit L2; only indices + output touch HBM.
// ---------------------------------------------------------------------------
__global__ __launch_bounds__(BLOCK) void hetero_gather(
    const unsigned int* __restrict__ src32, const unsigned int* __restrict__ dst32,
    const float4* __restrict__ tsrc, const float4* __restrict__ tdst,
    float* __restrict__ out, int n_edges, const int* __restrict__ flag) {
  int shift = flag[0];
  int gtid  = blockIdx.x * BLOCK + threadIdx.x;
  int e0    = gtid * 4;
  if (e0 + 3 < n_edges) {
    unsigned s[4], d[4];
    const uint4* sp = (const uint4*)(src32 + ((size_t)e0 << shift));
    const uint4* dp = (const uint4*)(dst32 + ((size_t)e0 << shift));
    if (shift) {  // int64: 8 dwords, take even words
      uint4 a = sp[0], bb = sp[1];
      s[0] = a.x; s[1] = a.z; s[2] = bb.x; s[3] = bb.z;
      uint4 c = dp[0], dd = dp[1];
      d[0] = c.x; d[1] = c.z; d[2] = dd.x; d[3] = dd.z;
    } else {      // int32: 4 dwords
      uint4 a = sp[0]; s[0] = a.x; s[1] = a.y; s[2] = a.z; s[3] = a.w;
      uint4 c = dp[0]; d[0] = c.x; d[1] = c.y; d[2] = c.z; d[3] = c.w;
    }
    float r[12];
#pragma unroll
    for (int k = 0; k < 4; ++k) {
      float4 a = tsrc[s[k]];
      float4 c = tdst[d[k]];
      r[k * 3 + 0] = a.x + c.x;
      r[k * 3 + 1] = a.y + c.y;
      r[k * 3 + 2] = a.z + c.z;
    }
    float4* o4 = (float4*)(out + (size_t)e0 * 3);  // e0*12B, 16B aligned
    o4[0] = make_float4(r[0], r[1], r[2],  r[3]);
    o4[1] = make_float4(r[4], r[5], r[6],  r[7]);
    o4[2] = make_float4(r[8], r[9], r[10], r[11]);
  } else if (e0 < n_edges) {
    for (int e = e0; e < n_edges; ++e) {
      unsigned s = src32[(size_t)e << shift];
      unsigned d = dst32[(size_t)e << shift];
      float4 a = tsrc[s];
      float4 c = tdst[d];
      out[(size_t)e * 3 + 0] = a.x + c.x;
      out[(size_t)e * 3 + 1] = a.y + c.y;
      out[(size_t)e * 3 + 2] = a.z + c.z;
    }
  }
}

extern "C" void kernel_launch(void* const* d_in, const int* in_sizes, int n_in,
                              void* d_out, int out_size, void* d_ws, size_t ws_size,
                              hipStream_t stream) {
  const float*        h     = (const float*)d_in[0];
  const unsigned int* src32 = (const unsigned int*)d_in[1];
  const unsigned int* dst32 = (const unsigned int*)d_in[2];
  const float*        W     = (const float*)d_in[3];
  const float*        b     = (const float*)d_in[4];
  float*              out   = (float*)d_out;

  int n_nodes = in_sizes[0] / N_DIMS;  // 10000
  int n_edges = in_sizes[1];           // 500000

  char*   ws   = (char*)d_ws;
  float4* tsrc = (float4*)(ws);
  float4* tdst = (float4*)(ws + (size_t)n_nodes * sizeof(float4));
  int*    flag = (int*)(ws + 2 * (size_t)n_nodes * sizeof(float4));

  // Kernel 1: 8 nodes per wave, 4 waves per block.
  int proj_blocks = (n_nodes + 31) / 32;  // 313
  hetero_proj_detect<<<proj_blocks, BLOCK, 0, stream>>>(
      h, W, b, src32, tsrc, tdst, flag, n_nodes, n_edges);

  // Kernel 2: 4 edges per thread.
  int gather_blocks = (n_edges / 4 + BLOCK - 1) / BLOCK;  // 489
  hetero_gather<<<gather_blocks, BLOCK, 0, stream>>>(
      src32, dst32, tsrc, tdst, out, n_edges, flag);
}